// Round 11
// baseline (420.113 us; speedup 1.0000x reference)
//
#include <hip/hip_runtime.h>

typedef _Float16 f16x8 __attribute__((ext_vector_type(8)));
typedef float f32x4 __attribute__((ext_vector_type(4)));

__device__ __forceinline__ void gload16(const void* g, void* l) {
  __builtin_amdgcn_global_load_lds(
      (const __attribute__((address_space(1))) void*)g,
      (__attribute__((address_space(3))) void*)l, 16, 0, 0);
}

__device__ __forceinline__ void barfence() {
  asm volatile("" ::: "memory");
  __builtin_amdgcn_s_barrier();
  asm volatile("" ::: "memory");
}

// m204 bijective XCD swizzle
__device__ __forceinline__ int xcd_swz(int orig, int nwg) {
  int q = nwg >> 3, r = nwg & 7;
  int x = orig & 7, loc = orig >> 3;
  int base = (x < r) ? x * (q + 1) : r * (q + 1) + (x - r) * q;
  return base + loc;
}

// ---------------- all weight transposes in ONE launch ------------------------
struct WPtrs { const float* w[6]; _Float16* wt[6]; };
__global__ __launch_bounds__(256) void transpose_all(WPtrs p) {
  const int N = 1024;
  __shared__ float tile[32][33];
  int y = blockIdx.y, layer, ky;
  if (y < 16) { layer = 0; ky = y; }
  else { int t = y - 16; layer = 1 + (t >> 5); ky = t & 31; }
  int K = (layer == 0) ? 512 : 1024;
  const float* W = p.w[layer];
  _Float16* WT = p.wt[layer];
  int tx = threadIdx.x, ty = threadIdx.y;  // (32,8)
  int n0 = blockIdx.x * 32, k0 = ky * 32;
#pragma unroll
  for (int i = 0; i < 4; i++)
    tile[ty + i * 8][tx] = W[(long)(k0 + ty + i * 8) * N + (n0 + tx)];
  __syncthreads();
#pragma unroll
  for (int i = 0; i < 4; i++)
    WT[(long)(n0 + ty + i * 8) * K + (k0 + tx)] = (_Float16)tile[tx][ty + i * 8];
}

// ---------------- plain rows: f32 -> f16 cast (fallback path only) -----------
__global__ __launch_bounds__(256) void cast_f16(const float* __restrict__ in,
                                                _Float16* __restrict__ out, long n) {
  long i = ((long)blockIdx.x * 256 + threadIdx.x) * 4;
  if (i < n) {
    float4 v = *(const float4*)(in + i);
    typedef _Float16 f16x4 __attribute__((ext_vector_type(4)));
    f16x4 o = {(_Float16)v.x, (_Float16)v.y, (_Float16)v.z, (_Float16)v.w};
    *(f16x4*)(out + i) = o;
  }
}

// ---------------- exact per-row top-k corruption, 1 wave per row -------------
__global__ __launch_bounds__(256) void topk_corrupt(
    const float* __restrict__ noise, const float* __restrict__ x,
    const float* __restrict__ u, const float* __restrict__ mmin,
    const float* __restrict__ mmax, const int* __restrict__ kptr,
    _Float16* __restrict__ dplain, _Float16* __restrict__ dcorr,
    int xrow0, int nrows) {
  int lane = threadIdx.x & 63;
  int r = (blockIdx.x << 2) + (threadIdx.x >> 6);
  if (r >= nrows) return;
  long row = (long)xrow0 + r;
  long rb = row * 512 + lane * 8;
  float4 n0 = *(const float4*)(noise + rb);
  float4 n1 = *(const float4*)(noise + rb + 4);
  unsigned v[8] = {__float_as_uint(n0.x), __float_as_uint(n0.y),
                   __float_as_uint(n0.z), __float_as_uint(n0.w),
                   __float_as_uint(n1.x), __float_as_uint(n1.y),
                   __float_as_uint(n1.z), __float_as_uint(n1.w)};
  int kk = *kptr;
  unsigned T = 0;
  for (int bit = 30; bit >= 0; --bit) {
    unsigned Tp = T | (1u << bit);
    int c = 0;
#pragma unroll
    for (int j = 0; j < 8; j++) c += (int)__popcll(__ballot(v[j] >= Tp));
    if (c >= kk) T = Tp;
  }
  int cgt = 0;
  unsigned long long eqb[8];
#pragma unroll
  for (int j = 0; j < 8; j++) {
    cgt += (int)__popcll(__ballot(v[j] > T));
    eqb[j] = __ballot(v[j] == T);
  }
  int need = kk - cgt;
  unsigned long long below = (1ull << lane) - 1ull;
  int rank_base = 0;
#pragma unroll
  for (int j = 0; j < 8; j++) rank_base += (int)__popcll(eqb[j] & below);

  float4 x0 = *(const float4*)(x + rb);
  float4 x1 = *(const float4*)(x + rb + 4);
  float4 u0 = *(const float4*)(u + rb);
  float4 u1 = *(const float4*)(u + rb + 4);
  int col = lane * 8;
  float4 mn0 = *(const float4*)(mmin + col);
  float4 mn1 = *(const float4*)(mmin + col + 4);
  float4 mx0 = *(const float4*)(mmax + col);
  float4 mx1 = *(const float4*)(mmax + col + 4);
  float xs[8] = {x0.x, x0.y, x0.z, x0.w, x1.x, x1.y, x1.z, x1.w};
  float us[8] = {u0.x, u0.y, u0.z, u0.w, u1.x, u1.y, u1.z, u1.w};
  float mns[8] = {mn0.x, mn0.y, mn0.z, mn0.w, mn1.x, mn1.y, mn1.z, mn1.w};
  float mxs[8] = {mx0.x, mx0.y, mx0.z, mx0.w, mx1.x, mx1.y, mx1.z, mx1.w};

  f16x8 po, co;
  int loc = 0;
#pragma unroll
  for (int j = 0; j < 8; j++) {
    bool eq = (v[j] == T);
    int rank = rank_base + loc;
    bool m = (v[j] > T) || (eq && (rank < need));
    loc += eq ? 1 : 0;
    float rv = mns[j] + us[j] * (mxs[j] - mns[j]);
    float cv = m ? rv : xs[j];
    po[j] = (_Float16)xs[j];
    co[j] = (_Float16)cv;
  }
  long ob = (long)r * 512 + lane * 8;
  if (dplain) *(f16x8*)(dplain + ob) = po;
  *(f16x8*)(dcorr + ob) = co;
}

// ---------------- f16 GEMM: 128x128 tile, BK=64, 2 blocks/CU (TLP play) ------
// A: MxK row-major f16 (M mult of 128). BT: NxK row-major f16 (N=1024).
// 512 thr = 8 waves (2M x 4N), wave-tile 64x32 -> acc 32 VGPR; frags 48;
// total ~110 VGPR -> __launch_bounds__(512,4) = 4 waves/SIMD. LDS = 2buf x
// (A[128x64] + B[128x64]) = 64 KiB -> 2 blocks/CU. Per tile: {STAGE(t+1)
// issued FIRST (T14 split); 12 ds_reads; 16 MFMA; vmcnt(0); barrier} — the
// drain is hidden by the co-resident block's waves (TLP replaces counted-vmcnt
// ILP). Swizzle: proven round-5 chunk^(row&7) on 128B rows, both sides -> 0
// bank conflicts. WAR: STAGE(nbuf) after barrier ending t-1 whose reads of
// nbuf completed in-phase (lgkm) before that barrier. Safe.
template <bool RELU, bool OUTF32>
__global__ __launch_bounds__(512, 4) void gemm2b(const _Float16* __restrict__ A,
                                                 const _Float16* __restrict__ BT,
                                                 const float* __restrict__ bias,
                                                 void* __restrict__ Cout, int K) {
  const int N = 1024;
  __shared__ _Float16 S[2][2][8192];  // [buf][A,B][128 rows x 64 f16] = 64 KiB
  int tid = threadIdx.x;
  int lane = tid & 63, wave = tid >> 6;
  int wr = wave >> 2, wc = wave & 3;  // 2M x 4N
  int logical = xcd_swz(blockIdx.x, gridDim.x);
  long arow0 = (long)(logical >> 3) * 128;  // bn-fast: 8 col-blocks share A
  int bcol0 = (logical & 7) * 128;

  // staging: unit = 128 rows x 8 chunks(16B); source chunk = cl ^ (row&7)
  int srow = tid >> 3;                       // 0..63
  int scg = (tid & 7) ^ (srow & 7);          // pre-swizzled source chunk
  const _Float16* gA[2];
  const _Float16* gB[2];
#pragma unroll
  for (int j = 0; j < 2; j++) {
    gA[j] = A + (arow0 + j * 64 + srow) * (long)K + scg * 8;
    gB[j] = BT + (long)(bcol0 + j * 64 + srow) * K + scg * 8;
  }
  int lo = tid * 8;

#define STG(BUF, T)                                     \
  do {                                                  \
    gload16(gA[0] + (T) * 64, &S[BUF][0][lo]);          \
    gload16(gA[1] + (T) * 64, &S[BUF][0][4096 + lo]);   \
    gload16(gB[0] + (T) * 64, &S[BUF][1][lo]);          \
    gload16(gB[1] + (T) * 64, &S[BUF][1][4096 + lo]);   \
  } while (0)

  // fragment read offsets: row r, chunk (kk*4+g)^(lr&7)  [round-5 proven]
  int lr = lane & 15, g = lane >> 4, e = lr & 7;
  int cs0 = ((0 * 4 + g) ^ e) * 8;
  int cs1 = ((1 * 4 + g) ^ e) * 8;
  int aoff[4], boff[2];
#pragma unroll
  for (int mf = 0; mf < 4; mf++) aoff[mf] = (wr * 64 + mf * 16 + lr) * 64;
#pragma unroll
  for (int nf = 0; nf < 2; nf++) boff[nf] = (wc * 32 + nf * 16 + lr) * 64;

  f16x8 af[4][2], bf[2][2];
  f32x4 acc[4][2] = {};  // [mf][nf]

  int NT = K / 64;
  STG(0, 0);
  asm volatile("s_waitcnt vmcnt(0)" ::: "memory");
  barfence();

  for (int t = 0; t < NT; ++t) {
    int buf = t & 1, nbuf = buf ^ 1;
    if (t + 1 < NT) STG(nbuf, t + 1);  // issue early: lands during compute
#pragma unroll
    for (int mf = 0; mf < 4; mf++) {
      af[mf][0] = *(const f16x8*)&S[buf][0][aoff[mf] + cs0];
      af[mf][1] = *(const f16x8*)&S[buf][0][aoff[mf] + cs1];
    }
#pragma unroll
    for (int nf = 0; nf < 2; nf++) {
      bf[nf][0] = *(const f16x8*)&S[buf][1][boff[nf] + cs0];
      bf[nf][1] = *(const f16x8*)&S[buf][1][boff[nf] + cs1];
    }
    __builtin_amdgcn_s_setprio(1);
#pragma unroll
    for (int mf = 0; mf < 4; mf++)
#pragma unroll
      for (int nf = 0; nf < 2; nf++)
#pragma unroll
        for (int kk = 0; kk < 2; kk++)
          acc[mf][nf] = __builtin_amdgcn_mfma_f32_16x16x32_f16(
              af[mf][kk], bf[nf][kk], acc[mf][nf], 0, 0, 0);
    __builtin_amdgcn_s_setprio(0);
    if (t + 1 < NT) {
      asm volatile("s_waitcnt vmcnt(0)" ::: "memory");
      barfence();
    }
  }
#undef STG

  // epilogue: C/D layout col=lane&15, row=(lane>>4)*4+reg
  int r0 = (lane >> 4) * 4;
  float bv[2];
#pragma unroll
  for (int nf = 0; nf < 2; nf++) bv[nf] = bias[bcol0 + wc * 32 + nf * 16 + lr];
#pragma unroll
  for (int mf = 0; mf < 4; mf++) {
    long rowb = arow0 + wr * 64 + mf * 16 + r0;
#pragma unroll
    for (int nf = 0; nf < 2; nf++) {
      int col = bcol0 + wc * 32 + nf * 16 + lr;
#pragma unroll
      for (int rr = 0; rr < 4; rr++) {
        float v = acc[mf][nf][rr] + bv[nf];
        if (RELU) v = fmaxf(v, 0.f);
        if (OUTF32) {
          // final output is write-once: nontemporal, keep L2 for operands
          __builtin_nontemporal_store(v, &((float*)Cout)[(rowb + rr) * N + col]);
        } else {
          ((_Float16*)Cout)[(rowb + rr) * N + col] = (_Float16)v;
        }
      }
    }
  }
}

extern "C" void kernel_launch(void* const* d_in, const int* in_sizes, int n_in,
                              void* d_out, int out_size, void* d_ws, size_t ws_size,
                              hipStream_t stream) {
  const float* x    = (const float*)d_in[0];
  const float* rn   = (const float*)d_in[1];
  const float* ur   = (const float*)d_in[2];
  const float* mmin = (const float*)d_in[3];
  const float* mmax = (const float*)d_in[4];
  const float* W[6]  = {(const float*)d_in[5],  (const float*)d_in[7],  (const float*)d_in[9],
                        (const float*)d_in[11], (const float*)d_in[13], (const float*)d_in[15]};
  const float* Bi[6] = {(const float*)d_in[6],  (const float*)d_in[8],  (const float*)d_in[10],
                        (const float*)d_in[12], (const float*)d_in[14], (const float*)d_in[16]};
  const int* kptr = (const int*)d_in[17];
  float* out = (float*)d_out;

  const long B = 16384;
  const int E = 1024;
  const int Ks[6] = {512, 1024, 1024, 1024, 1024, 1024};

  // ws layout: [wT0..wT5][both_chunk][h0][h1]
  char* ws = (char*)d_ws;
  _Float16* wT[6];
  size_t off = 0;
  for (int i = 0; i < 6; i++) { wT[i] = (_Float16*)(ws + off); off += (size_t)Ks[i] * E * 2; }
  size_t rem = (ws_size > off) ? ws_size - off : 0;
  long R = 32768;
  while (R > 128 && (size_t)R * 5120 > rem) R >>= 1;   // both(1024R)+2*h(4096R) bytes

  _Float16* bothc = (_Float16*)(ws + off);
  _Float16* h0 = bothc + R * 512;
  _Float16* h1 = h0 + R * 1024;

  // one fused launch for all weight transposes
  WPtrs wp;
  for (int i = 0; i < 6; i++) { wp.w[i] = W[i]; wp.wt[i] = wT[i]; }
  transpose_all<<<dim3(E / 32, 16 + 5 * 32), dim3(32, 8), 0, stream>>>(wp);

  for (long r0 = 0; r0 < 2 * B; r0 += R) {
    // ---- build rows [r0, r0+R) of `both` in f16 ----
    if (R == 2 * B) {
      topk_corrupt<<<dim3((unsigned)(B / 4)), dim3(256), 0, stream>>>(
          rn, x, ur, mmin, mmax, kptr, bothc, bothc + B * 512, 0, (int)B);
    } else {
      long plainEnd = (r0 < B) ? ((r0 + R < B) ? (r0 + R) : B) : r0;
      long p1 = plainEnd - r0;
      if (p1 > 0) {
        long n = p1 * 512;
        long blocks = (n / 4 + 255) / 256;
        cast_f16<<<dim3((unsigned)blocks), dim3(256), 0, stream>>>(x + r0 * 512, bothc, n);
      }
      long c0 = (r0 > B) ? r0 : B;
      long p2 = (r0 + R) - c0;
      if (p2 > 0) {
        topk_corrupt<<<dim3((unsigned)((p2 + 3) / 4)), dim3(256), 0, stream>>>(
            rn, x, ur, mmin, mmax, kptr, (_Float16*)nullptr,
            bothc + (c0 - r0) * 512, (int)(c0 - B), (int)p2);
      }
    }
    // ---- 6-layer MLP on this chunk ----
    dim3 gg((unsigned)((R / 128) * 8)), gb(512);
    gemm2b<true,  false><<<gg, gb, 0, stream>>>(bothc, wT[0], Bi[0], (void*)h0, 512);
    gemm2b<true,  false><<<gg, gb, 0, stream>>>(h0,    wT[1], Bi[1], (void*)h1, 1024);
    gemm2b<true,  false><<<gg, gb, 0, stream>>>(h1,    wT[2], Bi[2], (void*)h0, 1024);
    gemm2b<false, false><<<gg, gb, 0, stream>>>(h0,    wT[3], Bi[3], (void*)h1, 1024);
    gemm2b<true,  false><<<gg, gb, 0, stream>>>(h1,    wT[4], Bi[4], (void*)h0, 1024);
    gemm2b<false, true ><<<gg, gb, 0, stream>>>(h0,    wT[5], Bi[5],
                                                 (void*)(out + r0 * 1024), 1024);
  }
}

// Round 12
// 403.251 us; speedup vs baseline: 1.0418x; 1.0418x over previous
//
#include <hip/hip_runtime.h>

typedef _Float16 f16x8 __attribute__((ext_vector_type(8)));
typedef float f32x4 __attribute__((ext_vector_type(4)));

__device__ __forceinline__ void gload16(const void* g, void* l) {
  __builtin_amdgcn_global_load_lds(
      (const __attribute__((address_space(1))) void*)g,
      (__attribute__((address_space(3))) void*)l, 16, 0, 0);
}

__device__ __forceinline__ void barfence() {
  asm volatile("" ::: "memory");
  __builtin_amdgcn_s_barrier();
  asm volatile("" ::: "memory");
}

// m204 bijective XCD swizzle
__device__ __forceinline__ int xcd_swz(int orig, int nwg) {
  int q = nwg >> 3, r = nwg & 7;
  int x = orig & 7, loc = orig >> 3;
  int base = (x < r) ? x * (q + 1) : r * (q + 1) + (x - r) * q;
  return base + loc;
}

struct WPtrs { const float* w[6]; _Float16* wt[6]; };

// ---------------- topk row body (1 wave = 1 row) ------------------------------
__device__ __forceinline__ void topk_row(
    const float* __restrict__ noise, const float* __restrict__ x,
    const float* __restrict__ u, const float* __restrict__ mmin,
    const float* __restrict__ mmax, int kk, _Float16* __restrict__ dplain,
    _Float16* __restrict__ dcorr, long row, long orow) {
  int lane = threadIdx.x & 63;
  long rb = row * 512 + lane * 8;
  float4 n0 = *(const float4*)(noise + rb);
  float4 n1 = *(const float4*)(noise + rb + 4);
  unsigned v[8] = {__float_as_uint(n0.x), __float_as_uint(n0.y),
                   __float_as_uint(n0.z), __float_as_uint(n0.w),
                   __float_as_uint(n1.x), __float_as_uint(n1.y),
                   __float_as_uint(n1.z), __float_as_uint(n1.w)};
  unsigned T = 0;
  for (int bit = 30; bit >= 0; --bit) {
    unsigned Tp = T | (1u << bit);
    int c = 0;
#pragma unroll
    for (int j = 0; j < 8; j++) c += (int)__popcll(__ballot(v[j] >= Tp));
    if (c >= kk) T = Tp;
  }
  int cgt = 0;
  unsigned long long eqb[8];
#pragma unroll
  for (int j = 0; j < 8; j++) {
    cgt += (int)__popcll(__ballot(v[j] > T));
    eqb[j] = __ballot(v[j] == T);
  }
  int need = kk - cgt;
  unsigned long long below = (1ull << lane) - 1ull;
  int rank_base = 0;
#pragma unroll
  for (int j = 0; j < 8; j++) rank_base += (int)__popcll(eqb[j] & below);

  float4 x0 = *(const float4*)(x + rb);
  float4 x1 = *(const float4*)(x + rb + 4);
  float4 u0 = *(const float4*)(u + rb);
  float4 u1 = *(const float4*)(u + rb + 4);
  int col = lane * 8;
  float4 mn0 = *(const float4*)(mmin + col);
  float4 mn1 = *(const float4*)(mmin + col + 4);
  float4 mx0 = *(const float4*)(mmax + col);
  float4 mx1 = *(const float4*)(mmax + col + 4);
  float xs[8] = {x0.x, x0.y, x0.z, x0.w, x1.x, x1.y, x1.z, x1.w};
  float us[8] = {u0.x, u0.y, u0.z, u0.w, u1.x, u1.y, u1.z, u1.w};
  float mns[8] = {mn0.x, mn0.y, mn0.z, mn0.w, mn1.x, mn1.y, mn1.z, mn1.w};
  float mxs[8] = {mx0.x, mx0.y, mx0.z, mx0.w, mx1.x, mx1.y, mx1.z, mx1.w};

  f16x8 po, co;
  int loc = 0;
#pragma unroll
  for (int j = 0; j < 8; j++) {
    bool eq = (v[j] == T);
    int rank = rank_base + loc;
    bool m = (v[j] > T) || (eq && (rank < need));
    loc += eq ? 1 : 0;
    float rv = mns[j] + us[j] * (mxs[j] - mns[j]);
    float cv = m ? rv : xs[j];
    po[j] = (_Float16)xs[j];
    co[j] = (_Float16)cv;
  }
  long ob = orow * 512 + lane * 8;
  if (dplain) *(f16x8*)(dplain + ob) = po;
  *(f16x8*)(dcorr + ob) = co;
}

// ---------------- fused prep: topk+cast rows AND all weight transposes -------
// blocks [0, ntopk): 4 rows each (topk + plain cast).
// blocks [ntopk, ntopk+5632): weight transpose, W (KxN f32) -> WT (NxK f16).
__global__ __launch_bounds__(256) void prep_all(
    const float* __restrict__ noise, const float* __restrict__ x,
    const float* __restrict__ u, const float* __restrict__ mmin,
    const float* __restrict__ mmax, const int* __restrict__ kptr,
    _Float16* __restrict__ dplain, _Float16* __restrict__ dcorr,
    WPtrs p, int ntopk) {
  const int N = 1024;
  if ((int)blockIdx.x < ntopk) {
    int r = ((int)blockIdx.x << 2) + (threadIdx.x >> 6);
    topk_row(noise, x, u, mmin, mmax, *kptr, dplain, dcorr, r, r);
    return;
  }
  int b = (int)blockIdx.x - ntopk;
  int bx = b & 31;          // n-block 0..31
  int y = b >> 5;           // 0..175
  __shared__ float tile[32][33];
  int layer, ky;
  if (y < 16) { layer = 0; ky = y; }
  else { int t = y - 16; layer = 1 + (t >> 5); ky = t & 31; }
  int K = (layer == 0) ? 512 : 1024;
  const float* W = p.w[layer];
  _Float16* WT = p.wt[layer];
  int tx = threadIdx.x & 31, ty = threadIdx.x >> 5;  // (32,8)
  int n0 = bx * 32, k0 = ky * 32;
#pragma unroll
  for (int i = 0; i < 4; i++)
    tile[ty + i * 8][tx] = W[(long)(k0 + ty + i * 8) * N + (n0 + tx)];
  __syncthreads();
#pragma unroll
  for (int i = 0; i < 4; i++)
    WT[(long)(n0 + ty + i * 8) * K + (k0 + tx)] = (_Float16)tile[tx][ty + i * 8];
}

// ---------------- fallback kernels (R < 2B path) ------------------------------
__global__ __launch_bounds__(256) void transpose_all(WPtrs p) {
  const int N = 1024;
  __shared__ float tile[32][33];
  int y = blockIdx.y, layer, ky;
  if (y < 16) { layer = 0; ky = y; }
  else { int t = y - 16; layer = 1 + (t >> 5); ky = t & 31; }
  int K = (layer == 0) ? 512 : 1024;
  const float* W = p.w[layer];
  _Float16* WT = p.wt[layer];
  int tx = threadIdx.x, ty = threadIdx.y;  // (32,8)
  int n0 = blockIdx.x * 32, k0 = ky * 32;
#pragma unroll
  for (int i = 0; i < 4; i++)
    tile[ty + i * 8][tx] = W[(long)(k0 + ty + i * 8) * N + (n0 + tx)];
  __syncthreads();
#pragma unroll
  for (int i = 0; i < 4; i++)
    WT[(long)(n0 + ty + i * 8) * K + (k0 + tx)] = (_Float16)tile[tx][ty + i * 8];
}

__global__ __launch_bounds__(256) void cast_f16(const float* __restrict__ in,
                                                _Float16* __restrict__ out, long n) {
  long i = ((long)blockIdx.x * 256 + threadIdx.x) * 4;
  if (i < n) {
    float4 v = *(const float4*)(in + i);
    typedef _Float16 f16x4 __attribute__((ext_vector_type(4)));
    f16x4 o = {(_Float16)v.x, (_Float16)v.y, (_Float16)v.z, (_Float16)v.w};
    *(f16x4*)(out + i) = o;
  }
}

__global__ __launch_bounds__(256) void topk_corrupt(
    const float* __restrict__ noise, const float* __restrict__ x,
    const float* __restrict__ u, const float* __restrict__ mmin,
    const float* __restrict__ mmax, const int* __restrict__ kptr,
    _Float16* __restrict__ dcorr, int xrow0, int nrows) {
  int r = ((int)blockIdx.x << 2) + (threadIdx.x >> 6);
  if (r >= nrows) return;
  topk_row(noise, x, u, mmin, mmax, *kptr, (_Float16*)nullptr, dcorr,
           (long)xrow0 + r, r);
}

// ---------------- f16 GEMM A: 256x256, BK=64, 3 fused phases/tile ------------
// (round-10 verified: best for compute-dominated layers L0..L4)
template <bool RELU, bool OUTF32>
__global__ __launch_bounds__(512, 2) void gemm8p(const _Float16* __restrict__ A,
                                                 const _Float16* __restrict__ BT,
                                                 const float* __restrict__ bias,
                                                 void* __restrict__ Cout, int K) {
  const int N = 1024;
  __shared__ _Float16 S[2][4][8192];  // [buf][A0,A1,B0,B1][128 rows x 64 f16]
  int tid = threadIdx.x;
  int lane = tid & 63, wave = tid >> 6;
  int wr = wave >> 2, wc = wave & 3;  // 2 x 4
  int logical = xcd_swz(blockIdx.x, gridDim.x);
  long arow0 = (long)(logical >> 2) * 256;
  int bcol0 = (logical & 3) * 256;

  int srow = tid >> 3;
  int scg = (tid & 7) ^ (srow & 7);
  const _Float16* gA[2][2];
  const _Float16* gB[2][2];
#pragma unroll
  for (int h = 0; h < 2; h++)
#pragma unroll
    for (int j = 0; j < 2; j++) {
      gA[h][j] = A + (arow0 + h * 128 + j * 64 + srow) * (long)K + scg * 8;
      gB[h][j] = BT + (long)(bcol0 + h * 128 + j * 64 + srow) * K + scg * 8;
    }
  int lo = tid * 8;

#define STG_A(BUF, H, T)                                   \
  do {                                                     \
    gload16(gA[H][0] + (T) * 64, &S[BUF][H][lo]);          \
    gload16(gA[H][1] + (T) * 64, &S[BUF][H][4096 + lo]);   \
  } while (0)
#define STG_B(BUF, H, T)                                      \
  do {                                                        \
    gload16(gB[H][0] + (T) * 64, &S[BUF][2 + H][lo]);         \
    gload16(gB[H][1] + (T) * 64, &S[BUF][2 + H][4096 + lo]);  \
  } while (0)

  int lr = lane & 15, g = lane >> 4, e = lr & 7;
  int cs0 = ((0 * 4 + g) ^ e) * 8;
  int cs1 = ((1 * 4 + g) ^ e) * 8;
  int aoff[4], boff[2];
#pragma unroll
  for (int mf = 0; mf < 4; mf++) aoff[mf] = (wr * 64 + mf * 16 + lr) * 64;
#pragma unroll
  for (int nf = 0; nf < 2; nf++) boff[nf] = (wc * 32 + nf * 16 + lr) * 64;

  f16x8 af0[4][2], af1[4][2];
  f16x8 bf0[2][2], bf1[2][2];
  f32x4 acc[2][2][4][2] = {};

#define LDA(DST, BUF, MQ)                                            \
  do {                                                               \
    _Pragma("unroll") for (int mf = 0; mf < 4; mf++) {               \
      DST[mf][0] = *(const f16x8*)&S[BUF][MQ][aoff[mf] + cs0];       \
      DST[mf][1] = *(const f16x8*)&S[BUF][MQ][aoff[mf] + cs1];       \
    }                                                                \
  } while (0)
#define LDB(DST, BUF, NQ)                                            \
  do {                                                               \
    _Pragma("unroll") for (int nf = 0; nf < 2; nf++) {               \
      DST[nf][0] = *(const f16x8*)&S[BUF][2 + NQ][boff[nf] + cs0];   \
      DST[nf][1] = *(const f16x8*)&S[BUF][2 + NQ][boff[nf] + cs1];   \
    }                                                                \
  } while (0)
#define MFMA_Q(AF, BF, MQ, NQ)                                       \
  do {                                                               \
    __builtin_amdgcn_s_setprio(1);                                   \
    _Pragma("unroll") for (int mf = 0; mf < 4; mf++)                 \
    _Pragma("unroll") for (int nf = 0; nf < 2; nf++)                 \
    _Pragma("unroll") for (int kk = 0; kk < 2; kk++)                 \
      acc[MQ][NQ][mf][nf] = __builtin_amdgcn_mfma_f32_16x16x32_f16(  \
          AF[mf][kk], BF[nf][kk], acc[MQ][NQ][mf][nf], 0, 0, 0);     \
    __builtin_amdgcn_s_setprio(0);                                   \
  } while (0)

  int NT = K / 64;
  STG_B(0, 0, 0); STG_B(0, 1, 0); STG_A(0, 0, 0); STG_A(0, 1, 0);
  asm volatile("s_waitcnt vmcnt(2)" ::: "memory");
  barfence();
  LDA(af0, 0, 0);
  LDB(bf1, 0, 1);

  for (int t = 0; t < NT; ++t) {
    int buf = t & 1, nbuf = buf ^ 1;
    LDB(bf0, buf, 0);
    if (t + 1 < NT) { STG_B(nbuf, 0, t + 1); STG_B(nbuf, 1, t + 1); }
    MFMA_Q(af0, bf0, 0, 0);
    if (t + 1 < NT) asm volatile("s_waitcnt vmcnt(4)" ::: "memory");
    else            asm volatile("s_waitcnt vmcnt(0)" ::: "memory");
    barfence();
    LDA(af1, buf, 1);
    if (t + 1 < NT) { STG_A(nbuf, 0, t + 1); STG_A(nbuf, 1, t + 1); }
    MFMA_Q(af0, bf1, 0, 1);
    MFMA_Q(af1, bf1, 1, 1);
    if (t + 1 < NT) asm volatile("s_waitcnt vmcnt(2)" ::: "memory");
    barfence();
    if (t + 1 < NT) { LDA(af0, nbuf, 0); LDB(bf1, nbuf, 1); }
    MFMA_Q(af1, bf0, 1, 0);
    if (t + 1 < NT) barfence();
  }
#undef STG_A
#undef STG_B
#undef LDA
#undef LDB
#undef MFMA_Q

  int r0 = (lane >> 4) * 4;
  float bv[2][2];
#pragma unroll
  for (int nq = 0; nq < 2; nq++)
#pragma unroll
    for (int nf = 0; nf < 2; nf++)
      bv[nq][nf] = bias[bcol0 + nq * 128 + wc * 32 + nf * 16 + lr];
#pragma unroll
  for (int mq = 0; mq < 2; mq++)
#pragma unroll
    for (int mf = 0; mf < 4; mf++) {
      long rowb = arow0 + mq * 128 + wr * 64 + mf * 16 + r0;
#pragma unroll
      for (int nq = 0; nq < 2; nq++)
#pragma unroll
        for (int nf = 0; nf < 2; nf++) {
          int col = bcol0 + nq * 128 + wc * 32 + nf * 16 + lr;
#pragma unroll
          for (int rr = 0; rr < 4; rr++) {
            float v = acc[mq][nq][mf][nf][rr] + bv[nq][nf];
            if (RELU) v = fmaxf(v, 0.f);
            if (OUTF32) ((float*)Cout)[(rowb + rr) * N + col] = v;
            else ((_Float16*)Cout)[(rowb + rr) * N + col] = (_Float16)v;
          }
        }
    }
}

// ---------------- f16 GEMM B: 128x128, 2 blocks/CU, NT stores (final layer) --
// (round-11 verified: best for the store-heavy f32 output layer)
template <bool RELU, bool OUTF32>
__global__ __launch_bounds__(512, 4) void gemm2b(const _Float16* __restrict__ A,
                                                 const _Float16* __restrict__ BT,
                                                 const float* __restrict__ bias,
                                                 void* __restrict__ Cout, int K) {
  const int N = 1024;
  __shared__ _Float16 S[2][2][8192];
  int tid = threadIdx.x;
  int lane = tid & 63, wave = tid >> 6;
  int wr = wave >> 2, wc = wave & 3;
  int logical = xcd_swz(blockIdx.x, gridDim.x);
  long arow0 = (long)(logical >> 3) * 128;
  int bcol0 = (logical & 7) * 128;

  int srow = tid >> 3;
  int scg = (tid & 7) ^ (srow & 7);
  const _Float16* gA[2];
  const _Float16* gB[2];
#pragma unroll
  for (int j = 0; j < 2; j++) {
    gA[j] = A + (arow0 + j * 64 + srow) * (long)K + scg * 8;
    gB[j] = BT + (long)(bcol0 + j * 64 + srow) * K + scg * 8;
  }
  int lo = tid * 8;

#define STG(BUF, T)                                     \
  do {                                                  \
    gload16(gA[0] + (T) * 64, &S[BUF][0][lo]);          \
    gload16(gA[1] + (T) * 64, &S[BUF][0][4096 + lo]);   \
    gload16(gB[0] + (T) * 64, &S[BUF][1][lo]);          \
    gload16(gB[1] + (T) * 64, &S[BUF][1][4096 + lo]);   \
  } while (0)

  int lr = lane & 15, g = lane >> 4, e = lr & 7;
  int cs0 = ((0 * 4 + g) ^ e) * 8;
  int cs1 = ((1 * 4 + g) ^ e) * 8;
  int aoff[4], boff[2];
#pragma unroll
  for (int mf = 0; mf < 4; mf++) aoff[mf] = (wr * 64 + mf * 16 + lr) * 64;
#pragma unroll
  for (int nf = 0; nf < 2; nf++) boff[nf] = (wc * 32 + nf * 16 + lr) * 64;

  f16x8 af[4][2], bf[2][2];
  f32x4 acc[4][2] = {};

  int NT = K / 64;
  STG(0, 0);
  asm volatile("s_waitcnt vmcnt(0)" ::: "memory");
  barfence();

  for (int t = 0; t < NT; ++t) {
    int buf = t & 1, nbuf = buf ^ 1;
    if (t + 1 < NT) STG(nbuf, t + 1);
#pragma unroll
    for (int mf = 0; mf < 4; mf++) {
      af[mf][0] = *(const f16x8*)&S[buf][0][aoff[mf] + cs0];
      af[mf][1] = *(const f16x8*)&S[buf][0][aoff[mf] + cs1];
    }
#pragma unroll
    for (int nf = 0; nf < 2; nf++) {
      bf[nf][0] = *(const f16x8*)&S[buf][1][boff[nf] + cs0];
      bf[nf][1] = *(const f16x8*)&S[buf][1][boff[nf] + cs1];
    }
    __builtin_amdgcn_s_setprio(1);
#pragma unroll
    for (int mf = 0; mf < 4; mf++)
#pragma unroll
      for (int nf = 0; nf < 2; nf++)
#pragma unroll
        for (int kk = 0; kk < 2; kk++)
          acc[mf][nf] = __builtin_amdgcn_mfma_f32_16x16x32_f16(
              af[mf][kk], bf[nf][kk], acc[mf][nf], 0, 0, 0);
    __builtin_amdgcn_s_setprio(0);
    if (t + 1 < NT) {
      asm volatile("s_waitcnt vmcnt(0)" ::: "memory");
      barfence();
    }
  }
#undef STG

  int r0 = (lane >> 4) * 4;
  float bv[2];
#pragma unroll
  for (int nf = 0; nf < 2; nf++) bv[nf] = bias[bcol0 + wc * 32 + nf * 16 + lr];
#pragma unroll
  for (int mf = 0; mf < 4; mf++) {
    long rowb = arow0 + wr * 64 + mf * 16 + r0;
#pragma unroll
    for (int nf = 0; nf < 2; nf++) {
      int col = bcol0 + wc * 32 + nf * 16 + lr;
#pragma unroll
      for (int rr = 0; rr < 4; rr++) {
        float v = acc[mf][nf][rr] + bv[nf];
        if (RELU) v = fmaxf(v, 0.f);
        if (OUTF32) {
          __builtin_nontemporal_store(v, &((float*)Cout)[(rowb + rr) * N + col]);
        } else {
          ((_Float16*)Cout)[(rowb + rr) * N + col] = (_Float16)v;
        }
      }
    }
  }
}

extern "C" void kernel_launch(void* const* d_in, const int* in_sizes, int n_in,
                              void* d_out, int out_size, void* d_ws, size_t ws_size,
                              hipStream_t stream) {
  const float* x    = (const float*)d_in[0];
  const float* rn   = (const float*)d_in[1];
  const float* ur   = (const float*)d_in[2];
  const float* mmin = (const float*)d_in[3];
  const float* mmax = (const float*)d_in[4];
  const float* W[6]  = {(const float*)d_in[5],  (const float*)d_in[7],  (const float*)d_in[9],
                        (const float*)d_in[11], (const float*)d_in[13], (const float*)d_in[15]};
  const float* Bi[6] = {(const float*)d_in[6],  (const float*)d_in[8],  (const float*)d_in[10],
                        (const float*)d_in[12], (const float*)d_in[14], (const float*)d_in[16]};
  const int* kptr = (const int*)d_in[17];
  float* out = (float*)d_out;

  const long B = 16384;
  const int E = 1024;
  const int Ks[6] = {512, 1024, 1024, 1024, 1024, 1024};

  char* ws = (char*)d_ws;
  _Float16* wT[6];
  size_t off = 0;
  for (int i = 0; i < 6; i++) { wT[i] = (_Float16*)(ws + off); off += (size_t)Ks[i] * E * 2; }
  size_t rem = (ws_size > off) ? ws_size - off : 0;
  long R = 32768;
  while (R > 256 && (size_t)R * 5120 > rem) R >>= 1;

  _Float16* bothc = (_Float16*)(ws + off);
  _Float16* h0 = bothc + R * 512;
  _Float16* h1 = h0 + R * 1024;

  WPtrs wp;
  for (int i = 0; i < 6; i++) { wp.w[i] = W[i]; wp.wt[i] = wT[i]; }

  if (R == 2 * B) {
    // fused prep: topk/cast (4096 blocks) + all weight transposes (5632 blocks)
    int ntopk = (int)(B / 4);
    prep_all<<<dim3((unsigned)(ntopk + 32 * 176)), dim3(256), 0, stream>>>(
        rn, x, ur, mmin, mmax, kptr, bothc, bothc + B * 512, wp, ntopk);

    dim3 gg((unsigned)((R / 256) * 4)), gb(512);
    dim3 gg2((unsigned)((R / 128) * 8));
    gemm8p<true,  false><<<gg, gb, 0, stream>>>(bothc, wT[0], Bi[0], (void*)h0, 512);
    gemm8p<true,  false><<<gg, gb, 0, stream>>>(h0,    wT[1], Bi[1], (void*)h1, 1024);
    gemm8p<true,  false><<<gg, gb, 0, stream>>>(h1,    wT[2], Bi[2], (void*)h0, 1024);
    gemm8p<false, false><<<gg, gb, 0, stream>>>(h0,    wT[3], Bi[3], (void*)h1, 1024);
    gemm8p<true,  false><<<gg, gb, 0, stream>>>(h1,    wT[4], Bi[4], (void*)h0, 1024);
    gemm2b<false, true ><<<gg2, gb, 0, stream>>>(h0,   wT[5], Bi[5], (void*)out, 1024);
  } else {
    transpose_all<<<dim3(E / 32, 16 + 5 * 32), dim3(32, 8), 0, stream>>>(wp);
    for (long r0 = 0; r0 < 2 * B; r0 += R) {
      long plainEnd = (r0 < B) ? ((r0 + R < B) ? (r0 + R) : B) : r0;
      long p1 = plainEnd - r0;
      if (p1 > 0) {
        long n = p1 * 512;
        long blocks = (n / 4 + 255) / 256;
        cast_f16<<<dim3((unsigned)blocks), dim3(256), 0, stream>>>(x + r0 * 512, bothc, n);
      }
      long c0 = (r0 > B) ? r0 : B;
      long p2 = (r0 + R) - c0;
      if (p2 > 0) {
        topk_corrupt<<<dim3((unsigned)((p2 + 3) / 4)), dim3(256), 0, stream>>>(
            rn, x, ur, mmin, mmax, kptr, bothc + (c0 - r0) * 512,
            (int)(c0 - B), (int)p2);
      }
      dim3 gg((unsigned)((R / 256) * 4)), gb(512);
      dim3 gg2((unsigned)((R / 128) * 8));
      gemm8p<true,  false><<<gg, gb, 0, stream>>>(bothc, wT[0], Bi[0], (void*)h0, 512);
      gemm8p<true,  false><<<gg, gb, 0, stream>>>(h0,    wT[1], Bi[1], (void*)h1, 1024);
      gemm8p<true,  false><<<gg, gb, 0, stream>>>(h1,    wT[2], Bi[2], (void*)h0, 1024);
      gemm8p<false, false><<<gg, gb, 0, stream>>>(h0,    wT[3], Bi[3], (void*)h1, 1024);
      gemm8p<true,  false><<<gg, gb, 0, stream>>>(h1,    wT[4], Bi[4], (void*)h0, 1024);
      gemm2b<false, true ><<<gg2, gb, 0, stream>>>(h0,   wT[5], Bi[5],
                                                   (void*)(out + r0 * 1024), 1024);
    }
  }
}